// Round 5
// baseline (190.758 us; speedup 1.0000x reference)
//
#include <hip/hip_runtime.h>

// VQ quantizer: N=131072 rows, K=1024 codes, D=10, fp32.
// R5: row-per-lane (NO cross-lane reduce, no LDS in hot loop) + codebook
// broadcast via wave-uniform global_load_dwordx4 with depth-4 manual
// software pipeline (4 static float4x3 buffers). kbase derives from
// threadIdx (divergence-marked) so loads stay on the VECTOR memory pipe
// (R4's readfirstlane forced s_load -> scalar-latency-bound at 48 SGPRs).
// Prep kernel pads codes to 48B stride with ms=-0.5*||e||^2 at slot 10.
// 1024 blocks x 256 thr (4 waves): block owns 128 rows (2/lane); each wave
// scans K/4=256 codes; LDS merge (ascending wave, strict > => first-index
// tie-break == argmin semantics). Same fmaf chain order as R1-R4 (absmax 0.0).

constexpr int N = 131072;
constexpr int K = 1024;
constexpr int D = 10;
constexpr int THREADS = 256;          // 4 waves
constexpr int BLOCKS = 1024;          // 4 blocks/CU -> 16 waves/CU
constexpr int ROWS_PER_BLOCK = 128;
constexpr int ROWS_PER_LANE = 2;
constexpr int KSPLIT = 4;             // one codebook quarter per wave
constexpr int KPW = K / KSPLIT;       // 256
constexpr int KPAD = 8;               // prefetch overrun rows

// 12 floats (3 x float4) per code row: e0..e9, ms, 0
__device__ __attribute__((aligned(256))) float4 g_cb4[(K + KPAD) * 3];

__global__ __launch_bounds__(256) void prep_kernel(const float* __restrict__ E) {
    const int k = blockIdx.x * blockDim.x + threadIdx.x;
    if (k < K + KPAD) {
        const int src = (k < K) ? k : 0;          // pad rows: clone row 0
        float e[D];
        #pragma unroll
        for (int d = 0; d < D; ++d) e[d] = E[src * D + d];
        float s = 0.f;
        #pragma unroll
        for (int d = 0; d < D; ++d) s = fmaf(e[d], e[d], s);   // same chain as R1-R4
        const float ms = -0.5f * s;
        g_cb4[k * 3 + 0] = make_float4(e[0], e[1], e[2], e[3]);
        g_cb4[k * 3 + 1] = make_float4(e[4], e[5], e[6], e[7]);
        g_cb4[k * 3 + 2] = make_float4(e[8], e[9], ms, 0.f);
    }
}

__global__ __launch_bounds__(THREADS, 4) void vq_kernel(
    const float* __restrict__ x,
    const float* __restrict__ E,
    float* __restrict__ out,
    float* __restrict__ loss_out)
{
    __shared__ float sScore[KSPLIT][ROWS_PER_BLOCK];   // 2 KB
    __shared__ int   sIdx[KSPLIT][ROWS_PER_BLOCK];     // 2 KB

    const int tid  = threadIdx.x;
    const int lane = tid & 63;
    const int wave = tid >> 6;
    const int rowBase = blockIdx.x * ROWS_PER_BLOCK;

    // ---- this lane's 2 rows of x -> VGPRs ----
    float xr[ROWS_PER_LANE][D];
    #pragma unroll
    for (int j = 0; j < ROWS_PER_LANE; ++j) {
        const float* xp = x + (size_t)(rowBase + lane + 64 * j) * D;
        #pragma unroll
        for (int d = 0; d < D; d += 2) {          // rows 40B apart, 8B aligned
            float2 v = *reinterpret_cast<const float2*>(xp + d);
            xr[j][d]     = v.x;
            xr[j][d + 1] = v.y;
        }
    }

    // kbase is threadIdx-derived => divergence-marked => vector-pipe loads
    const int kbase = wave * KPW;
    const float4* __restrict__ cb = g_cb4 + (size_t)kbase * 3;

    float best[ROWS_PER_LANE];
    int   bidx[ROWS_PER_LANE];
    #pragma unroll
    for (int j = 0; j < ROWS_PER_LANE; ++j) { best[j] = -3.0e38f; bidx[j] = 0; }

    // ---- depth-4 software pipeline over the wave's 256 codes ----
    float4 a0, a1, a2, b0, b1, b2, c0, c1, c2, e0v, e1v, e2v;

#define RELOAD(B0, B1, B2, KOFF) {                  \
        const float4* p = cb + (KOFF) * 3;          \
        B0 = p[0]; B1 = p[1]; B2 = p[2]; }

#define COMPUTE(B0, B1, B2, KOFF) {                                  \
        const int kcur = kbase + (KOFF);                             \
        _Pragma("unroll")                                            \
        for (int j = 0; j < ROWS_PER_LANE; ++j) {                    \
            float acc = B2.z;              /* ms = -0.5*||e||^2 */   \
            acc = fmaf(xr[j][0], B0.x, acc);                         \
            acc = fmaf(xr[j][1], B0.y, acc);                         \
            acc = fmaf(xr[j][2], B0.z, acc);                         \
            acc = fmaf(xr[j][3], B0.w, acc);                         \
            acc = fmaf(xr[j][4], B1.x, acc);                         \
            acc = fmaf(xr[j][5], B1.y, acc);                         \
            acc = fmaf(xr[j][6], B1.z, acc);                         \
            acc = fmaf(xr[j][7], B1.w, acc);                         \
            acc = fmaf(xr[j][8], B2.x, acc);                         \
            acc = fmaf(xr[j][9], B2.y, acc);                         \
            const bool gt = acc > best[j];   /* strict >, ascending k */ \
            bidx[j] = gt ? kcur   : bidx[j];                         \
            best[j] = gt ? acc    : best[j];                         \
        } }

    RELOAD(a0, a1, a2, 0)
    RELOAD(b0, b1, b2, 1)
    RELOAD(c0, c1, c2, 2)
    RELOAD(e0v, e1v, e2v, 3)

    for (int kk = 0; kk < KPW; kk += 4) {
        COMPUTE(a0, a1, a2, kk)       RELOAD(a0, a1, a2, kk + 4)
        COMPUTE(b0, b1, b2, kk + 1)   RELOAD(b0, b1, b2, kk + 5)
        COMPUTE(c0, c1, c2, kk + 2)   RELOAD(c0, c1, c2, kk + 6)
        COMPUTE(e0v, e1v, e2v, kk + 3) RELOAD(e0v, e1v, e2v, kk + 7)
    }
#undef RELOAD
#undef COMPUTE

    // ---- publish per-wave winners ----
    #pragma unroll
    for (int j = 0; j < ROWS_PER_LANE; ++j) {
        const int r = lane + 64 * j;
        sScore[wave][r] = best[j];
        sIdx[wave][r]   = bidx[j];
    }
    __syncthreads();

    // ---- merge across waves + epilogue (first 128 threads: 1 row each) ----
    float lsum = 0.f;
    for (int r = tid; r < ROWS_PER_BLOCK; r += THREADS) {
        float bs = sScore[0][r];
        int   bi = sIdx[0][r];
        #pragma unroll
        for (int w = 1; w < KSPLIT; ++w) {
            const float s  = sScore[w][r];
            const int   i2 = sIdx[w][r];
            if (s > bs) { bs = s; bi = i2; }          // ascending wave order
        }
        const float* ep = E   + (size_t)bi * D;       // L2-hot gather
        const float* xp = x   + (size_t)(rowBase + r) * D;
        float*       op = out + (size_t)(rowBase + r) * D;
        #pragma unroll
        for (int d = 0; d < D; d += 2) {
            float2 ev = *reinterpret_cast<const float2*>(ep + d);
            float2 xw = *reinterpret_cast<const float2*>(xp + d);
            const float d0 = xw.x - ev.x;
            const float d1 = xw.y - ev.y;
            lsum = fmaf(d0, d0, lsum);
            lsum = fmaf(d1, d1, lsum);
            float2 o;
            o.x = xw.x + (ev.x - xw.x);               // literal STE expression
            o.y = xw.y + (ev.y - xw.y);
            *reinterpret_cast<float2*>(op + d) = o;
        }
    }

    // ---- loss reduction: wave shuffle -> one atomic per wave ----
    #pragma unroll
    for (int off = 32; off > 0; off >>= 1)
        lsum += __shfl_down(lsum, off, 64);
    if (lane == 0)
        atomicAdd(loss_out, lsum * (1.0f / ((float)N * (float)D)));
}

extern "C" void kernel_launch(void* const* d_in, const int* in_sizes, int n_in,
                              void* d_out, int out_size, void* d_ws, size_t ws_size,
                              hipStream_t stream) {
    const float* x = (const float*)d_in[0];   // encoder_embedding [N, D]
    const float* E = (const float*)d_in[1];   // embedding_weight  [K, D]
    float* out  = (float*)d_out;              // quantized_st [N*D] then loss [1]
    float* loss = out + (size_t)N * D;

    hipMemsetAsync(loss, 0, sizeof(float), stream);       // d_out re-poisoned
    prep_kernel<<<dim3((K + KPAD + 255) / 256), dim3(256), 0, stream>>>(E);
    vq_kernel<<<dim3(BLOCKS), dim3(THREADS), 0, stream>>>(x, E, out, loss);
}

// Round 6
// 109.627 us; speedup vs baseline: 1.7401x; 1.7401x over previous
//
#include <hip/hip_runtime.h>

// VQ quantizer: N=131072 rows, K=1024 codes, D=10, fp32.
// R6: MFMA path. Score = x.e - 0.5||e||^2 computed by mfma_f32_32x32x16_bf16
// with exact fp32->3xbf16 operand splits (6 product terms: hh,mh,hm,mm,lh,hl;
// dropped terms ~1.5e-6 abs). ms=-0.5||e||^2 is triple-split into spare
// k-slots 10..12 of the eh-fragment against bf16(1.0) in the xh-fragment.
// Layout (CDNA4 standard): A(M=32 codes x K=16): lane m=L&31, k=(L>>5)*8+i.
// B(K=16 x N=32 rows): lane n=L&31, same k.  C/D: col=lane&31 (x-row),
// row=(reg&3)+8*(reg>>2)+4*(lane>>5) (HW-verified m74/m101).
// Per block (512 thr, 8 waves): stage 96KB prepacked E-fragment table to LDS;
// each wave owns 64 rows (2 row-tiles interleaved), builds its B-fragments
// once, loops 32 code-tiles x 12 MFMA, tracks per-lane argmax (ascending code
// order => strict > keeps first index, == argmin), one xor-32 merge at end.

typedef __attribute__((ext_vector_type(8))) short short8;
typedef __attribute__((ext_vector_type(16))) float f32x16;

constexpr int N = 131072;
constexpr int K = 1024;
constexpr int D = 10;
constexpr int TILES = 32;              // K / 32
constexpr int THREADS = 512;           // 8 waves
constexpr int BLOCKS = 256;            // 512 rows per block
constexpr int ROWS_PER_WAVE = 64;      // 2 row-tiles of 32
constexpr int AFRAG_N = TILES * 3 * 64;            // 6144 float4 = 96 KB
constexpr int SMEM_A_BYTES = AFRAG_N * 16;
constexpr int SMEM_B_PER_WAVE = ROWS_PER_WAVE * 96; // 3 variants x 32B per row
constexpr int SMEM_BYTES = SMEM_A_BYTES + 8 * SMEM_B_PER_WAVE;  // 147456

__device__ float4 g_afrag[AFRAG_N];

__device__ inline unsigned short f2bf(float f) {        // RNE fp32->bf16
    unsigned u = __float_as_uint(f);
    u += 0x7FFFu + ((u >> 16) & 1u);
    return (unsigned short)(u >> 16);
}
__device__ inline float bf2f(unsigned short h) {
    return __uint_as_float(((unsigned)h) << 16);
}

// Pre-pack E fragments: g_afrag[(tile*3+v)*64 + lane] = lane's 8 bf16 slots.
// v0: eh[0..9], msh, msm, msl, 0,0,0   v1: em[0..9], 0...   v2: el[0..9], 0...
__global__ __launch_bounds__(256) void prep_afrag(const float* __restrict__ E) {
    const int gid = blockIdx.x * blockDim.x + threadIdx.x;
    if (gid >= AFRAG_N) return;
    const int tile = gid / 192;
    const int rem  = gid % 192;
    const int v    = rem / 64;
    const int L    = rem % 64;
    const int code = tile * 32 + (L & 31);
    const int h    = L >> 5;

    float e[D];
    #pragma unroll
    for (int d = 0; d < D; ++d) e[d] = E[code * D + d];
    float s = 0.f;
    #pragma unroll
    for (int d = 0; d < D; ++d) s = fmaf(e[d], e[d], s);   // same chain as R1-R5
    const float ms = -0.5f * s;
    const unsigned short msh = f2bf(ms);
    const float r1 = ms - bf2f(msh);
    const unsigned short msm = f2bf(r1);
    const unsigned short msl = f2bf(r1 - bf2f(msm));

    unsigned short sl[8];
    #pragma unroll
    for (int i = 0; i < 8; ++i) {
        const int k = h * 8 + i;
        unsigned short o = 0;
        if (k < D) {
            const unsigned short eh = f2bf(e[k]);
            if (v == 0) o = eh;
            else {
                const float rm = e[k] - bf2f(eh);
                const unsigned short em = f2bf(rm);
                o = (v == 1) ? em : f2bf(rm - bf2f(em));
            }
        } else if (v == 0) {
            o = (k == 10) ? msh : (k == 11) ? msm : (k == 12) ? msl : (unsigned short)0;
        }
        sl[i] = o;
    }
    float4 w;
    unsigned* wp = (unsigned*)&w;
    #pragma unroll
    for (int q = 0; q < 4; ++q)
        wp[q] = (unsigned)sl[2 * q] | ((unsigned)sl[2 * q + 1] << 16);
    g_afrag[gid] = w;
}

__global__ __launch_bounds__(THREADS, 2) void vq_kernel(
    const float* __restrict__ x,
    const float* __restrict__ E,
    float* __restrict__ out,
    float* __restrict__ loss_out)
{
    extern __shared__ char smem[];
    float4* sA = (float4*)smem;                 // 96 KB fragment table
    char*   sB = smem + SMEM_A_BYTES;           // 8 x 6 KB B-slot staging

    const int tid  = threadIdx.x;
    const int lane = tid & 63;
    const int wave = tid >> 6;
    const int rtW  = blockIdx.x * (BLOCKS ? (N / BLOCKS) : 0) + wave * ROWS_PER_WAVE;

    // ---- stage E-fragment table into LDS (coalesced) ----
    for (int i = tid; i < AFRAG_N; i += THREADS) sA[i] = g_afrag[i];

    // ---- build this wave's B (x) fragments: lane writes row rtW+lane ----
    {
        const float* xp = x + (size_t)(rtW + lane) * D;
        float xv[D];
        #pragma unroll
        for (int d = 0; d < D; d += 2) {
            float2 t2 = *reinterpret_cast<const float2*>(xp + d);
            xv[d] = t2.x; xv[d + 1] = t2.y;
        }
        unsigned short XH[D], XM[D], XL[D];
        #pragma unroll
        for (int d = 0; d < D; ++d) {
            XH[d] = f2bf(xv[d]); const float r1 = xv[d] - bf2f(XH[d]);
            XM[d] = f2bf(r1);    XL[d] = f2bf(r1 - bf2f(XM[d]));
        }
        unsigned short slots[48];
        #pragma unroll
        for (int s = 0; s < 16; ++s) {
            slots[s]      = (s < D) ? XH[s]
                          : (s <= 12 ? (unsigned short)0x3F80 : (unsigned short)0); // bf16 1.0
            slots[16 + s] = (s < D) ? XM[s] : (unsigned short)0;
            slots[32 + s] = (s < D) ? XL[s] : (unsigned short)0;
        }
        float4* bp = (float4*)(sB + wave * SMEM_B_PER_WAVE + lane * 96);
        #pragma unroll
        for (int q = 0; q < 6; ++q) {
            float4 w; unsigned* wp = (unsigned*)&w;
            #pragma unroll
            for (int p = 0; p < 4; ++p)
                wp[p] = (unsigned)slots[q * 8 + 2 * p] | ((unsigned)slots[q * 8 + 2 * p + 1] << 16);
            bp[q] = w;
        }
    }
    __syncthreads();

    // ---- read B fragments (reused across all 32 code-tiles) ----
    const char* myB = sB + wave * SMEM_B_PER_WAVE;
    const int n   = lane & 31;
    const int h16 = (lane >> 5) * 16;
#define RDB(j, v) (*reinterpret_cast<const short8*>(myB + ((j) * 32 + n) * 96 + (v) * 32 + h16))
    const short8 b00 = RDB(0, 0), b01 = RDB(0, 1), b02 = RDB(0, 2);
    const short8 b10 = RDB(1, 0), b11 = RDB(1, 1), b12 = RDB(1, 2);
#undef RDB

    float best0 = -3.0e38f, best1 = -3.0e38f;
    int   bidx0 = 0,        bidx1 = 0;
    const int hibase = (lane >> 5) * 4;

    // ---- main loop: 32 code-tiles x (3 A-frag reads + 12 MFMA + argmax) ----
    for (int t = 0; t < TILES; ++t) {
        const short8 a0 = *reinterpret_cast<const short8*>(&sA[(t * 3 + 0) * 64 + lane]);
        const short8 a1 = *reinterpret_cast<const short8*>(&sA[(t * 3 + 1) * 64 + lane]);
        const short8 a2 = *reinterpret_cast<const short8*>(&sA[(t * 3 + 2) * 64 + lane]);
        f32x16 c0, c1;
        #pragma unroll
        for (int i = 0; i < 16; ++i) { c0[i] = 0.f; c1[i] = 0.f; }
        // 6 split-terms per row-tile, two row-tiles interleaved (dep distance 2)
        c0 = __builtin_amdgcn_mfma_f32_32x32x16_bf16(a0, b00, c0, 0, 0, 0);  // hh + ms
        c1 = __builtin_amdgcn_mfma_f32_32x32x16_bf16(a0, b10, c1, 0, 0, 0);
        c0 = __builtin_amdgcn_mfma_f32_32x32x16_bf16(a0, b01, c0, 0, 0, 0);  // eh.xm
        c1 = __builtin_amdgcn_mfma_f32_32x32x16_bf16(a0, b11, c1, 0, 0, 0);
        c0 = __builtin_amdgcn_mfma_f32_32x32x16_bf16(a0, b02, c0, 0, 0, 0);  // eh.xl
        c1 = __builtin_amdgcn_mfma_f32_32x32x16_bf16(a0, b12, c1, 0, 0, 0);
        c0 = __builtin_amdgcn_mfma_f32_32x32x16_bf16(a1, b00, c0, 0, 0, 0);  // em.xh
        c1 = __builtin_amdgcn_mfma_f32_32x32x16_bf16(a1, b10, c1, 0, 0, 0);
        c0 = __builtin_amdgcn_mfma_f32_32x32x16_bf16(a1, b01, c0, 0, 0, 0);  // em.xm
        c1 = __builtin_amdgcn_mfma_f32_32x32x16_bf16(a1, b11, c1, 0, 0, 0);
        c0 = __builtin_amdgcn_mfma_f32_32x32x16_bf16(a2, b00, c0, 0, 0, 0);  // el.xh
        c1 = __builtin_amdgcn_mfma_f32_32x32x16_bf16(a2, b10, c1, 0, 0, 0);

        const int tb = t * 32 + hibase;
        #pragma unroll
        for (int r = 0; r < 16; ++r) {                 // rows ascend with r
            const int ci = tb + ((r & 3) + 8 * (r >> 2));
            const bool g0 = c0[r] > best0;             // strict >: first idx wins
            bidx0 = g0 ? ci : bidx0;  best0 = g0 ? c0[r] : best0;
            const bool g1 = c1[r] > best1;
            bidx1 = g1 ? ci : bidx1;  best1 = g1 ? c1[r] : best1;
        }
    }

    // ---- merge lane-halves (codes interleave: explicit idx tie-break) ----
    {
        float pb = __shfl_xor(best0, 32, 64);
        int   pi = __shfl_xor(bidx0, 32, 64);
        bool take = (pb > best0) || (pb == best0 && pi < bidx0);
        best0 = take ? pb : best0;  bidx0 = take ? pi : bidx0;
        pb = __shfl_xor(best1, 32, 64);
        pi = __shfl_xor(bidx1, 32, 64);
        take = (pb > best1) || (pb == best1 && pi < bidx1);
        best1 = take ? pb : best1;  bidx1 = take ? pi : bidx1;
    }

    // ---- epilogue: lane L owns row rtW+L (half selects row-tile) ----
    const int   bi = (lane >> 5) ? bidx1 : bidx0;
    const float* ep = E   + (size_t)bi * D;            // L2-hot gather (40KB)
    const float* xp = x   + (size_t)(rtW + lane) * D;
    float*       op = out + (size_t)(rtW + lane) * D;
    float lsum = 0.f;
    #pragma unroll
    for (int d = 0; d < D; d += 2) {
        float2 ev = *reinterpret_cast<const float2*>(ep + d);
        float2 xw = *reinterpret_cast<const float2*>(xp + d);
        const float d0 = xw.x - ev.x, d1 = xw.y - ev.y;
        lsum = fmaf(d0, d0, lsum);  lsum = fmaf(d1, d1, lsum);
        float2 o;
        o.x = xw.x + (ev.x - xw.x);                    // literal STE expression
        o.y = xw.y + (ev.y - xw.y);
        *reinterpret_cast<float2*>(op + d) = o;
    }
    #pragma unroll
    for (int off = 32; off > 0; off >>= 1)
        lsum += __shfl_down(lsum, off, 64);
    if (lane == 0)
        atomicAdd(loss_out, lsum * (1.0f / ((float)N * (float)D)));
}

extern "C" void kernel_launch(void* const* d_in, const int* in_sizes, int n_in,
                              void* d_out, int out_size, void* d_ws, size_t ws_size,
                              hipStream_t stream) {
    const float* x = (const float*)d_in[0];   // encoder_embedding [N, D]
    const float* E = (const float*)d_in[1];   // embedding_weight  [K, D]
    float* out  = (float*)d_out;              // quantized_st [N*D] then loss [1]
    float* loss = out + (size_t)N * D;

    hipMemsetAsync(loss, 0, sizeof(float), stream);       // d_out re-poisoned
    prep_afrag<<<dim3(AFRAG_N / 256), dim3(256), 0, stream>>>(E);
    hipFuncSetAttribute((const void*)vq_kernel,
                        hipFuncAttributeMaxDynamicSharedMemorySize, SMEM_BYTES);
    vq_kernel<<<dim3(BLOCKS), dim3(THREADS), SMEM_BYTES, stream>>>(x, E, out, loss);
}

// Round 8
// 93.487 us; speedup vs baseline: 2.0405x; 1.1726x over previous
//
#include <hip/hip_runtime.h>

// VQ quantizer: N=131072 rows, K=1024 codes, D=10, fp32.
// R7 (resubmit; prior round was a broker timeout, no data).
// Register-resident A. Score = x.e - 0.5||e||^2 via mfma_f32_32x32x16_bf16
// with exact fp32->3xbf16 splits, 6 product terms (hh,hm,hl,mh,mm,lh) in the
// SAME accumulation order as R6 (absmax 0.0 verified). ms=-0.5||e||^2 triple-
// split rides k-slots 10..12 of A-v0 against bf16(1.0) in B-v0.
// Structure: 512 blocks x 512 thr (8 waves), __launch_bounds__(512,4) => <=128
// VGPR => 4 waves/SIMD, 2 blocks/CU. Wave w owns code-tiles w*4..w*4+3 as 12
// short8 VGPRs (loaded once). Block loops 8 row-groups of 32 rows; per group
// threads 0-31 build the B-table (3KB LDS, [variant][half][row] layout ->
// conflict-free ds_read_b128), every wave scans its 4 tiles (12 MFMA per tile
// pair, dual accumulators), argmax with inline-const local code id lci=t*16+r
// (3 VALU/reg), decode once, xor-32 half merge (explicit idx tie-break), LDS
// merge across waves (ascending wave = ascending code => strict > keeps first
// index == argmin semantics). Epilogue by threads 0-31 per group.

typedef __attribute__((ext_vector_type(8))) short short8;
typedef __attribute__((ext_vector_type(16))) float f32x16;

constexpr int N = 131072;
constexpr int K = 1024;
constexpr int D = 10;
constexpr int TILES = 32;              // K / 32
constexpr int THREADS = 512;           // 8 waves
constexpr int BLOCKS = 512;
constexpr int GROUPS = 8;              // row-groups per block
constexpr int RPG = 32;                // rows per group; 512*8*32 = N
constexpr int TPW = 4;                 // tiles per wave
constexpr int AFRAG_N = TILES * 3 * 64;

__device__ float4 g_afrag[AFRAG_N];

__device__ inline unsigned short f2bf(float f) {        // RNE fp32->bf16
    unsigned u = __float_as_uint(f);
    u += 0x7FFFu + ((u >> 16) & 1u);
    return (unsigned short)(u >> 16);
}
__device__ inline float bf2f(unsigned short h) {
    return __uint_as_float(((unsigned)h) << 16);
}

// Pre-pack E fragments (UNCHANGED from R6, verified absmax 0.0):
// g_afrag[(tile*3+v)*64 + L]; v0: eh[0..9],msh,msm,msl,0,0,0; v1: em; v2: el.
__global__ __launch_bounds__(256) void prep_afrag(const float* __restrict__ E) {
    const int gid = blockIdx.x * blockDim.x + threadIdx.x;
    if (gid >= AFRAG_N) return;
    const int tile = gid / 192;
    const int rem  = gid % 192;
    const int v    = rem / 64;
    const int L    = rem % 64;
    const int code = tile * 32 + (L & 31);
    const int h    = L >> 5;

    float e[D];
    #pragma unroll
    for (int d = 0; d < D; ++d) e[d] = E[code * D + d];
    float s = 0.f;
    #pragma unroll
    for (int d = 0; d < D; ++d) s = fmaf(e[d], e[d], s);   // same chain as R1-R6
    const float ms = -0.5f * s;
    const unsigned short msh = f2bf(ms);
    const float r1 = ms - bf2f(msh);
    const unsigned short msm = f2bf(r1);
    const unsigned short msl = f2bf(r1 - bf2f(msm));

    unsigned short sl[8];
    #pragma unroll
    for (int i = 0; i < 8; ++i) {
        const int k = h * 8 + i;
        unsigned short o = 0;
        if (k < D) {
            const unsigned short eh = f2bf(e[k]);
            if (v == 0) o = eh;
            else {
                const float rm = e[k] - bf2f(eh);
                const unsigned short em = f2bf(rm);
                o = (v == 1) ? em : f2bf(rm - bf2f(em));
            }
        } else if (v == 0) {
            o = (k == 10) ? msh : (k == 11) ? msm : (k == 12) ? msl : (unsigned short)0;
        }
        sl[i] = o;
    }
    float4 w;
    unsigned* wp = (unsigned*)&w;
    #pragma unroll
    for (int q = 0; q < 4; ++q)
        wp[q] = (unsigned)sl[2 * q] | ((unsigned)sl[2 * q + 1] << 16);
    g_afrag[gid] = w;
}

// Build one row's B fragments into the LDS table: sB[(v*2+h)*32 + row].
// Slot content identical to R6's B build (absmax 0.0 verified).
__device__ inline void build_b_row(const float* __restrict__ x, int grow,
                                   int row, short8* __restrict__ sB) {
    const float* xp = x + (size_t)grow * D;
    float xv[D];
    #pragma unroll
    for (int d = 0; d < D; d += 2) {
        float2 t2 = *reinterpret_cast<const float2*>(xp + d);
        xv[d] = t2.x; xv[d + 1] = t2.y;
    }
    unsigned short XH[D], XM[D], XL[D];
    #pragma unroll
    for (int d = 0; d < D; ++d) {
        XH[d] = f2bf(xv[d]); const float r1 = xv[d] - bf2f(XH[d]);
        XM[d] = f2bf(r1);    XL[d] = f2bf(r1 - bf2f(XM[d]));
    }
    unsigned short slots[48];
    #pragma unroll
    for (int s = 0; s < 16; ++s) {
        slots[s]      = (s < D) ? XH[s]
                      : (s <= 12 ? (unsigned short)0x3F80 : (unsigned short)0);
        slots[16 + s] = (s < D) ? XM[s] : (unsigned short)0;
        slots[32 + s] = (s < D) ? XL[s] : (unsigned short)0;
    }
    #pragma unroll
    for (int v = 0; v < 3; ++v)
        #pragma unroll
        for (int h = 0; h < 2; ++h) {
            short8 w;
            #pragma unroll
            for (int i = 0; i < 8; ++i) w[i] = (short)slots[v * 16 + h * 8 + i];
            sB[(v * 2 + h) * 32 + row] = w;
        }
}

#define MFMA __builtin_amdgcn_mfma_f32_32x32x16_bf16

__global__ __launch_bounds__(THREADS, 4) void vq_kernel(
    const float* __restrict__ x,
    const float* __restrict__ E,
    float* __restrict__ out,
    float* __restrict__ loss_out)
{
    __shared__ short8 sB[6 * 32];          // 3 KB  [(v*2+h)*32 + row]
    __shared__ float  sScore[8][RPG];      // 1 KB
    __shared__ int    sIdx[8][RPG];        // 1 KB

    const int tid  = threadIdx.x;
    const int lane = tid & 63;
    const int wave = tid >> 6;
    const int n    = lane & 31;
    const int hf   = lane >> 5;
    const int hibase = hf * 4;
    const int wtile  = wave * TPW;
    const int blockRow = blockIdx.x * (GROUPS * RPG);

    // ---- A fragments for this wave's 4 tiles -> 12 short8 VGPRs ----
    const short8* ga = (const short8*)g_afrag;
    short8 a[TPW][3];
    #pragma unroll
    for (int t = 0; t < TPW; ++t)
        #pragma unroll
        for (int v = 0; v < 3; ++v)
            a[t][v] = ga[((wtile + t) * 3 + v) * 64 + lane];

    // ---- B table for group 0 ----
    if (tid < RPG) build_b_row(x, blockRow + tid, tid, sB);
    __syncthreads();

    float lsum = 0.f;

    for (int g = 0; g < GROUPS; ++g) {
        const int rowBase = blockRow + g * RPG;

        // B fragments for this lane's row (conflict-free b128 broadcast-free)
        const short8 b0 = sB[(0 * 2 + hf) * 32 + n];
        const short8 b1 = sB[(1 * 2 + hf) * 32 + n];
        const short8 b2 = sB[(2 * 2 + hf) * 32 + n];

        float best = -3.0e38f;
        int   lci  = 0;                     // local code id: t*16 + r  (0..63)

        #pragma unroll
        for (int p = 0; p < TPW / 2; ++p) { // tile pairs: dep-distance-2 chains
            const int t0 = 2 * p, t1 = 2 * p + 1;
            f32x16 c0, c1;
            #pragma unroll
            for (int i = 0; i < 16; ++i) { c0[i] = 0.f; c1[i] = 0.f; }
            c0 = MFMA(a[t0][0], b0, c0, 0, 0, 0);  c1 = MFMA(a[t1][0], b0, c1, 0, 0, 0);
            c0 = MFMA(a[t0][0], b1, c0, 0, 0, 0);  c1 = MFMA(a[t1][0], b1, c1, 0, 0, 0);
            c0 = MFMA(a[t0][0], b2, c0, 0, 0, 0);  c1 = MFMA(a[t1][0], b2, c1, 0, 0, 0);
            c0 = MFMA(a[t0][1], b0, c0, 0, 0, 0);  c1 = MFMA(a[t1][1], b0, c1, 0, 0, 0);
            c0 = MFMA(a[t0][1], b1, c0, 0, 0, 0);  c1 = MFMA(a[t1][1], b1, c1, 0, 0, 0);
            c0 = MFMA(a[t0][2], b0, c0, 0, 0, 0);  c1 = MFMA(a[t1][2], b0, c1, 0, 0, 0);

            #pragma unroll
            for (int r = 0; r < 16; ++r) {         // ascending codes within half
                const bool gt = c0[r] > best;      // strict >: first idx wins
                lci  = gt ? (t0 * 16 + r) : lci;   // inline-const candidate
                best = fmaxf(best, c0[r]);
            }
            #pragma unroll
            for (int r = 0; r < 16; ++r) {
                const bool gt = c1[r] > best;
                lci  = gt ? (t1 * 16 + r) : lci;
                best = fmaxf(best, c1[r]);
            }
        }

        // decode local code id -> global code index
        const int tt = lci >> 4, rr = lci & 15;
        int bidx = (wtile + tt) * 32 + hibase + ((rr & 3) + 8 * (rr >> 2));

        // merge lane halves (codes interleave 4-apart: explicit idx tie-break)
        {
            const float pb = __shfl_xor(best, 32, 64);
            const int   pi = __shfl_xor(bidx, 32, 64);
            const bool take = (pb > best) || (pb == best && pi < bidx);
            best = take ? pb : best;  bidx = take ? pi : bidx;
        }
        if (lane < 32) { sScore[wave][n] = best; sIdx[wave][n] = bidx; }
        __syncthreads();

        if (tid < RPG) {
            // merge 8 waves (ascending wave = ascending code range)
            float bs = sScore[0][tid];
            int   bi = sIdx[0][tid];
            #pragma unroll
            for (int w = 1; w < 8; ++w) {
                const float s  = sScore[w][tid];
                const int   i2 = sIdx[w][tid];
                if (s > bs) { bs = s; bi = i2; }
            }
            // epilogue for row rowBase+tid
            const float* ep = E   + (size_t)bi * D;
            const float* xp = x   + (size_t)(rowBase + tid) * D;
            float*       op = out + (size_t)(rowBase + tid) * D;
            #pragma unroll
            for (int d = 0; d < D; d += 2) {
                float2 ev = *reinterpret_cast<const float2*>(ep + d);
                float2 xw = *reinterpret_cast<const float2*>(xp + d);
                const float d0 = xw.x - ev.x, d1 = xw.y - ev.y;
                lsum = fmaf(d0, d0, lsum);  lsum = fmaf(d1, d1, lsum);
                float2 o;
                o.x = xw.x + (ev.x - xw.x);        // literal STE expression
                o.y = xw.y + (ev.y - xw.y);
                *reinterpret_cast<float2*>(op + d) = o;
            }
            // build next group's B (safe: all waves read b0..b2 pre-sync)
            if (g + 1 < GROUPS)
                build_b_row(x, rowBase + RPG + tid, tid, sB);
        }
        __syncthreads();
    }

    // ---- loss: only wave 0 lanes 0-31 hold nonzero partials ----
    if (tid < 64) {
        #pragma unroll
        for (int off = 32; off > 0; off >>= 1)
            lsum += __shfl_down(lsum, off, 64);
        if (tid == 0)
            atomicAdd(loss_out, lsum * (1.0f / ((float)N * (float)D)));
    }
}

extern "C" void kernel_launch(void* const* d_in, const int* in_sizes, int n_in,
                              void* d_out, int out_size, void* d_ws, size_t ws_size,
                              hipStream_t stream) {
    const float* x = (const float*)d_in[0];   // encoder_embedding [N, D]
    const float* E = (const float*)d_in[1];   // embedding_weight  [K, D]
    float* out  = (float*)d_out;              // quantized_st [N*D] then loss [1]
    float* loss = out + (size_t)N * D;

    hipMemsetAsync(loss, 0, sizeof(float), stream);       // d_out re-poisoned
    prep_afrag<<<dim3(AFRAG_N / 256), dim3(256), 0, stream>>>(E);
    vq_kernel<<<dim3(BLOCKS), dim3(THREADS), 0, stream>>>(x, E, out, loss);
}